// Round 22
// baseline (87.639 us; speedup 1.0000x reference)
//
#include <hip/hip_runtime.h>
#include <hip/hip_bf16.h>

#define CS 384
#define CH 32
#define CZ 128
#define LL 384
#define NL 1536   // N*L
#define EPS 1e-5f

typedef float v4f __attribute__((ext_vector_type(4)));
typedef short s8v __attribute__((ext_vector_type(8)));          // 8 bf16 (MFMA A/B frag)
typedef unsigned short u8s __attribute__((ext_vector_type(8))); // 8 bf16 bits

static __device__ __forceinline__ unsigned short f2bf(float x) {
    unsigned int b = __float_as_uint(x);
    b += 0x7FFFu + ((b >> 16) & 1u);        // round-to-nearest-even
    return (unsigned short)(b >> 16);
}
static __device__ __forceinline__ v4f bf4_to_f4(ushort4 h) {
    v4f r;
    r.x = __uint_as_float((unsigned)h.x << 16);
    r.y = __uint_as_float((unsigned)h.y << 16);
    r.z = __uint_as_float((unsigned)h.z << 16);
    r.w = __uint_as_float((unsigned)h.w << 16);
    return r;
}

// ---------------- Kernel 1: LN + B = sn@W2+b2 -> Bf frags; Wo -> bf16 --------
// (identical to R21)
__global__ __launch_bounds__(256) void k_bf(
    const float* __restrict__ s, const float* __restrict__ g, const float* __restrict__ be,
    const float* __restrict__ W2, const float* __restrict__ pb2,
    const float* __restrict__ Wo,
    unsigned short* __restrict__ BfG, unsigned short* __restrict__ Wob)
{
    const int r0 = blockIdx.x * 4;
    const int t  = threadIdx.x;

    // Wo conversion: one v4f -> ushort4 per thread for idx < 32768
    {
        const int idx = blockIdx.x * 256 + t;
        if (idx < (CH * CH * CZ) / 4) {
            const v4f v = ((const v4f*)Wo)[idx];
            ushort4 h;
            h.x = f2bf(v.x); h.y = f2bf(v.y); h.z = f2bf(v.z); h.w = f2bf(v.w);
            ((ushort4*)Wob)[idx] = h;
        }
    }

    __shared__ float sn[4][392];
    __shared__ float part[4][2][32];

    // LN, wave per row
    {
        const int w = t >> 6, lane = t & 63;
        const float* srow = s + (size_t)(r0 + w) * CS;
        float x[6];
        #pragma unroll
        for (int k = 0; k < 6; ++k) x[k] = srow[lane + k * 64];
        float p = x[0] + x[1] + x[2] + x[3] + x[4] + x[5];
        #pragma unroll
        for (int m = 1; m < 64; m <<= 1) p += __shfl_xor(p, m);
        const float mu = p * (1.0f / CS);
        float q = 0.f;
        #pragma unroll
        for (int k = 0; k < 6; ++k) { float d = x[k] - mu; q += d * d; }
        #pragma unroll
        for (int m = 1; m < 64; m <<= 1) q += __shfl_xor(q, m);
        const float rstd = rsqrtf(q * (1.0f / CS) + EPS);
        #pragma unroll
        for (int k = 0; k < 6; ++k) {
            const int c = lane + k * 64;
            sn[w][c] = (x[k] - mu) * rstd * g[c] + be[c];
        }
    }
    __syncthreads();

    // matvec W2, c-halves
    {
        const int h = t & 31, ch = (t >> 5) & 1, rw = t >> 6;
        const float* snr = sn[rw];
        float acc = 0.f;
        const int c0 = ch * 192;
        #pragma unroll 8
        for (int c = c0; c < c0 + 192; ++c)
            acc += snr[c] * W2[c * CH + h];
        part[rw][ch][h] = acc;
    }
    __syncthreads();

    if (t < 128) {
        const int rw = t >> 5, h = t & 31;
        const float v = part[rw][0][h] + part[rw][1][h] + pb2[h];
        const int row = r0 + rw;
        const int n = row / LL, jr = row % LL;
        const int jt = jr >> 4, l16 = jr & 15;
        BfG[(((size_t)(n * 24 + jt)) * 64 + l16 + 16 * (h >> 3)) * 8 + (h & 7)] = f2bf(v);
    }
}

// ---------------- Kernel 2: r-pair fused prep + MFMA out ---------------------
// (identical to R21 except: final output stores are NONTEMPORAL — out-loop has
// zero VMEM loads, so NT cannot introduce waits; it only stops 302 MB of
// write-allocate from thrashing L2 where Wob/Bf/s live.)
__global__ __launch_bounds__(256, 3) void k_out_f(
    const float* __restrict__ s, const float* __restrict__ g, const float* __restrict__ be,
    const float* __restrict__ W1, const float* __restrict__ pb1,
    const unsigned short* __restrict__ Wob, const unsigned short* __restrict__ BfG,
    const float* __restrict__ bo, float* __restrict__ out)
{
    const int b  = blockIdx.x;      // 0..767
    const int r0 = b * 2;
    const int n  = r0 / LL;
    const int t  = threadIdx.x;
    const int l = t & 63, w = t >> 6;
    const int g2 = l >> 4, c16 = l & 15;
    const int li = l & 31, hi2 = l >> 5;

    __shared__ __align__(16) char smem[16384 + 32768];   // 48 KB
    unsigned short* MsubT = (unsigned short*)smem;        // [2][4096]: [rr][z*32+d]
    float (*sn)[392]      = (float(*)[392])(smem + 16384);           // 3136 B
    float (*part)[4][32]  = (float(*)[4][32])(smem + 16384 + 3200);  // 1024 B
    float* Afl            = (float*)(smem + 16384 + 3200 + 1024);    // [2][32]
    char*  bounceBase     = smem + 16384;                 // out-phase overlay (32 KB)

    // ---- LN rows r0, r0+1 (waves 0,1) ----
    if (w < 2) {
        const float* srow = s + (size_t)(r0 + w) * CS;
        float x[6];
        #pragma unroll
        for (int k = 0; k < 6; ++k) x[k] = srow[l + k * 64];
        float p = x[0] + x[1] + x[2] + x[3] + x[4] + x[5];
        #pragma unroll
        for (int m = 1; m < 64; m <<= 1) p += __shfl_xor(p, m);
        const float mu = p * (1.0f / CS);
        float q = 0.f;
        #pragma unroll
        for (int k = 0; k < 6; ++k) { float d = x[k] - mu; q += d * d; }
        #pragma unroll
        for (int m = 1; m < 64; m <<= 1) q += __shfl_xor(q, m);
        const float rstd = rsqrtf(q * (1.0f / CS) + EPS);
        #pragma unroll
        for (int k = 0; k < 6; ++k) {
            const int c = l + k * 64;
            sn[w][c] = (x[k] - mu) * rstd * g[c] + be[c];
        }
    }
    __syncthreads();

    // ---- a = sn@W1 + b1, both rows: h=t&31, cs=(t>>5)&3, rw=t>>7 ----
    {
        const int h = t & 31, cs = (t >> 5) & 3, rw = t >> 7;
        const float* snr = sn[rw];
        float acc = 0.f;
        const int c0 = cs * 96;
        #pragma unroll 8
        for (int c = c0; c < c0 + 96; ++c)
            acc += snr[c] * W1[c * CH + h];
        part[rw][cs][h] = acc;
    }
    __syncthreads();
    if (t < 64) {
        const int rw = t >> 5, h = t & 31;
        Afl[rw * 32 + h] = part[rw][0][h] + part[rw][1][h] + part[rw][2][h]
                         + part[rw][3][h] + pb1[h];
    }
    __syncthreads();

    // ---- M = a @ Wob (bf16), both rows -> MsubT (transposed, bf16) ----
    {
        const ushort4* Wo4 = (const ushort4*)Wob;   // 1024 ushort4 per c-row
        #pragma unroll
        for (int it = 0; it < 4; ++it) {
            const int col = t + it * 256;           // col = d*32 + zq
            const int d = col >> 5, zq = col & 31;  // z = zq*4 + j
            v4f a0 = (v4f)(0.f), a1 = (v4f)(0.f);
            #pragma unroll 8
            for (int c = 0; c < CH; ++c) {
                const v4f wv = bf4_to_f4(Wo4[(size_t)c * 1024 + col]);
                a0 += Afl[c] * wv;
                a1 += Afl[32 + c] * wv;
            }
            #pragma unroll
            for (int j = 0; j < 4; ++j) {
                const int z = zq * 4 + j;
                MsubT[z * 32 + d]        = f2bf(a0[j]);
                MsubT[4096 + z * 32 + d] = f2bf(a1[j]);
            }
        }
    }
    __syncthreads();   // MsubT ready; prep overlay region now free for bounce

    // ---- af + bias ----
    s8v af[6];
    {
        const s8v* Bfn = (const s8v*)(BfG + (size_t)n * 24 * 64 * 8);
        #pragma unroll
        for (int i = 0; i < 6; ++i) af[i] = Bfn[(w + i * 4) * 64 + l];
    }
    v4f bov[8];
    #pragma unroll
    for (int zt = 0; zt < 8; ++zt) bov[zt] = *(const v4f*)(bo + zt * 16 + g2 * 4);

    char* myl = bounceBase + w * 8192;

    #pragma unroll
    for (int rr = 0; rr < 2; ++rr) {
        // mf rebuild: one b128 LDS read per zt (contiguous 8 bf16 along d)
        s8v mf[8];
        {
            const unsigned short* Ms = MsubT + rr * 4096;
            #pragma unroll
            for (int zt = 0; zt < 8; ++zt)
                mf[zt] = *(const s8v*)(Ms + (zt * 16 + c16) * 32 + g2 * 8);
        }

        v4f* outv = (v4f*)(out + (size_t)(r0 + rr) * LL * CZ);

        #pragma unroll
        for (int i = 0; i < 6; ++i) {
            const int jt = w + i * 4;

            #pragma unroll
            for (int zt = 0; zt < 8; ++zt) {
                v4f d = __builtin_amdgcn_mfma_f32_16x16x32_bf16(mf[zt], af[i], (v4f)(0.f), 0, 0, 0);
                d += bov[zt];
                const int byte = (c16 << 9) + (((zt << 6) + (g2 << 4)) ^ ((c16 & 7) << 4));
                *(v4f*)(myl + byte) = d;
            }
            asm volatile("s_waitcnt lgkmcnt(0)" ::: "memory");

            #pragma unroll
            for (int i2 = 0; i2 < 8; ++i2) {
                const int rw2 = 2 * i2 + hi2;
                const int byte = (rw2 << 9) + (((li << 4)) ^ ((rw2 & 7) << 4));
                const v4f v = *(const v4f*)(myl + byte);
                __builtin_nontemporal_store(v, &outv[(size_t)(jt * 16 + rw2) * 32 + li]);
            }
        }
        __syncthreads();   // bounce reuse across rr
    }
}

extern "C" void kernel_launch(void* const* d_in, const int* in_sizes, int n_in,
                              void* d_out, int out_size, void* d_ws, size_t ws_size,
                              hipStream_t stream) {
    const float* s  = (const float*)d_in[0];
    const float* g  = (const float*)d_in[1];
    const float* be = (const float*)d_in[2];
    const float* W1 = (const float*)d_in[3];
    const float* b1 = (const float*)d_in[4];
    const float* W2 = (const float*)d_in[5];
    const float* b2 = (const float*)d_in[6];
    const float* Wo = (const float*)d_in[7];
    const float* bo = (const float*)d_in[8];
    float* out = (float*)d_out;

    // ws layout (bytes): Bf bf16 [0, 98304) | Wob bf16 [98304, 98304+262144)
    if (ws_size < 98304u + 262144u) return;  // fail visibly, no UB
    unsigned short* Bf  = (unsigned short*)d_ws;
    unsigned short* Wob = (unsigned short*)((char*)d_ws + 98304);

    k_bf   <<<NL / 4, 256, 0, stream>>>(s, g, be, W2, b2, Wo, Bf, Wob);
    k_out_f<<<NL / 2, 256, 0, stream>>>(s, g, be, W1, b1, Wob, Bf, bo, out);
}

// Round 23
// 78.770 us; speedup vs baseline: 1.1126x; 1.1126x over previous
//
#include <hip/hip_runtime.h>
#include <hip/hip_bf16.h>

#define CS 384
#define CH 32
#define CZ 128
#define LL 384
#define NL 1536   // N*L
#define EPS 1e-5f

typedef float v4f __attribute__((ext_vector_type(4)));
typedef short s8v __attribute__((ext_vector_type(8)));          // 8 bf16 (MFMA A/B frag)
typedef unsigned short u8s __attribute__((ext_vector_type(8))); // 8 bf16 bits

static __device__ __forceinline__ unsigned short f2bf(float x) {
    unsigned int b = __float_as_uint(x);
    b += 0x7FFFu + ((b >> 16) & 1u);        // round-to-nearest-even
    return (unsigned short)(b >> 16);
}
static __device__ __forceinline__ v4f bf4_to_f4(ushort4 h) {
    v4f r;
    r.x = __uint_as_float((unsigned)h.x << 16);
    r.y = __uint_as_float((unsigned)h.y << 16);
    r.z = __uint_as_float((unsigned)h.z << 16);
    r.w = __uint_as_float((unsigned)h.w << 16);
    return r;
}

// ---------------- Kernel 1: LN + B = sn@W2+b2 -> Bf frags; Wo -> bf16 --------
// (identical to R21)
__global__ __launch_bounds__(256) void k_bf(
    const float* __restrict__ s, const float* __restrict__ g, const float* __restrict__ be,
    const float* __restrict__ W2, const float* __restrict__ pb2,
    const float* __restrict__ Wo,
    unsigned short* __restrict__ BfG, unsigned short* __restrict__ Wob)
{
    const int r0 = blockIdx.x * 4;
    const int t  = threadIdx.x;

    // Wo conversion: one v4f -> ushort4 per thread for idx < 32768
    {
        const int idx = blockIdx.x * 256 + t;
        if (idx < (CH * CH * CZ) / 4) {
            const v4f v = ((const v4f*)Wo)[idx];
            ushort4 h;
            h.x = f2bf(v.x); h.y = f2bf(v.y); h.z = f2bf(v.z); h.w = f2bf(v.w);
            ((ushort4*)Wob)[idx] = h;
        }
    }

    __shared__ float sn[4][392];
    __shared__ float part[4][2][32];

    // LN, wave per row
    {
        const int w = t >> 6, lane = t & 63;
        const float* srow = s + (size_t)(r0 + w) * CS;
        float x[6];
        #pragma unroll
        for (int k = 0; k < 6; ++k) x[k] = srow[lane + k * 64];
        float p = x[0] + x[1] + x[2] + x[3] + x[4] + x[5];
        #pragma unroll
        for (int m = 1; m < 64; m <<= 1) p += __shfl_xor(p, m);
        const float mu = p * (1.0f / CS);
        float q = 0.f;
        #pragma unroll
        for (int k = 0; k < 6; ++k) { float d = x[k] - mu; q += d * d; }
        #pragma unroll
        for (int m = 1; m < 64; m <<= 1) q += __shfl_xor(q, m);
        const float rstd = rsqrtf(q * (1.0f / CS) + EPS);
        #pragma unroll
        for (int k = 0; k < 6; ++k) {
            const int c = lane + k * 64;
            sn[w][c] = (x[k] - mu) * rstd * g[c] + be[c];
        }
    }
    __syncthreads();

    // matvec W2, c-halves
    {
        const int h = t & 31, ch = (t >> 5) & 1, rw = t >> 6;
        const float* snr = sn[rw];
        float acc = 0.f;
        const int c0 = ch * 192;
        #pragma unroll 8
        for (int c = c0; c < c0 + 192; ++c)
            acc += snr[c] * W2[c * CH + h];
        part[rw][ch][h] = acc;
    }
    __syncthreads();

    if (t < 128) {
        const int rw = t >> 5, h = t & 31;
        const float v = part[rw][0][h] + part[rw][1][h] + pb2[h];
        const int row = r0 + rw;
        const int n = row / LL, jr = row % LL;
        const int jt = jr >> 4, l16 = jr & 15;
        BfG[(((size_t)(n * 24 + jt)) * 64 + l16 + 16 * (h >> 3)) * 8 + (h & 7)] = f2bf(v);
    }
}

// ---------------- Kernel 2: r-pair fused prep + MFMA out ---------------------
// R21 with ONE change: MsubT uses a 16B-block XOR swizzle
// (block' = (d>>3) ^ ((z>>2)&3)) so the transposed u16 scatter writes spread
// over 16 banks (was ~2 -> ~32-way conflict); reads remain one ds_read_b128
// per (rr,zt) at block = g2 ^ ((c16>>2)&3). Plain (cached) stores (NT reverted:
// __syncthreads drains vmcnt, NT acks at HBM latency -> R22's -6.6us).
__global__ __launch_bounds__(256, 3) void k_out_f(
    const float* __restrict__ s, const float* __restrict__ g, const float* __restrict__ be,
    const float* __restrict__ W1, const float* __restrict__ pb1,
    const unsigned short* __restrict__ Wob, const unsigned short* __restrict__ BfG,
    const float* __restrict__ bo, float* __restrict__ out)
{
    const int b  = blockIdx.x;      // 0..767
    const int r0 = b * 2;
    const int n  = r0 / LL;
    const int t  = threadIdx.x;
    const int l = t & 63, w = t >> 6;
    const int g2 = l >> 4, c16 = l & 15;
    const int li = l & 31, hi2 = l >> 5;

    __shared__ __align__(16) char smem[16384 + 32768];   // 48 KB
    unsigned short* MsubT = (unsigned short*)smem;        // [2][4096] u16, swizzled
    float (*sn)[392]      = (float(*)[392])(smem + 16384);           // 3136 B
    float (*part)[4][32]  = (float(*)[4][32])(smem + 16384 + 3200);  // 1024 B
    float* Afl            = (float*)(smem + 16384 + 3200 + 1024);    // [2][32]
    char*  bounceBase     = smem + 16384;                 // out-phase overlay (32 KB)

    // ---- LN rows r0, r0+1 (waves 0,1) ----
    if (w < 2) {
        const float* srow = s + (size_t)(r0 + w) * CS;
        float x[6];
        #pragma unroll
        for (int k = 0; k < 6; ++k) x[k] = srow[l + k * 64];
        float p = x[0] + x[1] + x[2] + x[3] + x[4] + x[5];
        #pragma unroll
        for (int m = 1; m < 64; m <<= 1) p += __shfl_xor(p, m);
        const float mu = p * (1.0f / CS);
        float q = 0.f;
        #pragma unroll
        for (int k = 0; k < 6; ++k) { float d = x[k] - mu; q += d * d; }
        #pragma unroll
        for (int m = 1; m < 64; m <<= 1) q += __shfl_xor(q, m);
        const float rstd = rsqrtf(q * (1.0f / CS) + EPS);
        #pragma unroll
        for (int k = 0; k < 6; ++k) {
            const int c = l + k * 64;
            sn[w][c] = (x[k] - mu) * rstd * g[c] + be[c];
        }
    }
    __syncthreads();

    // ---- a = sn@W1 + b1, both rows: h=t&31, cs=(t>>5)&3, rw=t>>7 ----
    {
        const int h = t & 31, cs = (t >> 5) & 3, rw = t >> 7;
        const float* snr = sn[rw];
        float acc = 0.f;
        const int c0 = cs * 96;
        #pragma unroll 8
        for (int c = c0; c < c0 + 96; ++c)
            acc += snr[c] * W1[c * CH + h];
        part[rw][cs][h] = acc;
    }
    __syncthreads();
    if (t < 64) {
        const int rw = t >> 5, h = t & 31;
        Afl[rw * 32 + h] = part[rw][0][h] + part[rw][1][h] + part[rw][2][h]
                         + part[rw][3][h] + pb1[h];
    }
    __syncthreads();

    // ---- M = a @ Wob (bf16), both rows -> MsubT (transposed, XOR-swizzled) --
    {
        const ushort4* Wo4 = (const ushort4*)Wob;   // 1024 ushort4 per c-row
        #pragma unroll
        for (int it = 0; it < 4; ++it) {
            const int col = t + it * 256;           // col = d*32 + zq
            const int d = col >> 5, zq = col & 31;  // z = zq*4 + j
            v4f a0 = (v4f)(0.f), a1 = (v4f)(0.f);
            #pragma unroll 8
            for (int c = 0; c < CH; ++c) {
                const v4f wv = bf4_to_f4(Wo4[(size_t)c * 1024 + col]);
                a0 += Afl[c] * wv;
                a1 += Afl[32 + c] * wv;
            }
            const int bsw = ((d >> 3) ^ (zq & 3)) * 8 + (d & 7);  // u16 idx in row
            #pragma unroll
            for (int j = 0; j < 4; ++j) {
                const int z = zq * 4 + j;           // z>>2 == zq
                MsubT[z * 32 + bsw]        = f2bf(a0[j]);
                MsubT[4096 + z * 32 + bsw] = f2bf(a1[j]);
            }
        }
    }
    __syncthreads();   // MsubT ready; prep overlay region now free for bounce

    // ---- af + bias ----
    s8v af[6];
    {
        const s8v* Bfn = (const s8v*)(BfG + (size_t)n * 24 * 64 * 8);
        #pragma unroll
        for (int i = 0; i < 6; ++i) af[i] = Bfn[(w + i * 4) * 64 + l];
    }
    v4f bov[8];
    #pragma unroll
    for (int zt = 0; zt < 8; ++zt) bov[zt] = *(const v4f*)(bo + zt * 16 + g2 * 4);

    char* myl = bounceBase + w * 8192;
    const int rblk = (g2 ^ ((c16 >> 2) & 3)) * 8;   // swizzled 16B block for reads

    #pragma unroll
    for (int rr = 0; rr < 2; ++rr) {
        // mf rebuild: one b128 LDS read per zt (swizzled block)
        s8v mf[8];
        {
            const unsigned short* Ms = MsubT + rr * 4096;
            #pragma unroll
            for (int zt = 0; zt < 8; ++zt)
                mf[zt] = *(const s8v*)(Ms + (zt * 16 + c16) * 32 + rblk);
        }

        v4f* outv = (v4f*)(out + (size_t)(r0 + rr) * LL * CZ);

        #pragma unroll
        for (int i = 0; i < 6; ++i) {
            const int jt = w + i * 4;

            #pragma unroll
            for (int zt = 0; zt < 8; ++zt) {
                v4f d = __builtin_amdgcn_mfma_f32_16x16x32_bf16(mf[zt], af[i], (v4f)(0.f), 0, 0, 0);
                d += bov[zt];
                const int byte = (c16 << 9) + (((zt << 6) + (g2 << 4)) ^ ((c16 & 7) << 4));
                *(v4f*)(myl + byte) = d;
            }
            asm volatile("s_waitcnt lgkmcnt(0)" ::: "memory");

            #pragma unroll
            for (int i2 = 0; i2 < 8; ++i2) {
                const int rw2 = 2 * i2 + hi2;
                const int byte = (rw2 << 9) + (((li << 4)) ^ ((rw2 & 7) << 4));
                const v4f v = *(const v4f*)(myl + byte);
                outv[(size_t)(jt * 16 + rw2) * 32 + li] = v;
            }
        }
        __syncthreads();   // bounce reuse across rr
    }
}

extern "C" void kernel_launch(void* const* d_in, const int* in_sizes, int n_in,
                              void* d_out, int out_size, void* d_ws, size_t ws_size,
                              hipStream_t stream) {
    const float* s  = (const float*)d_in[0];
    const float* g  = (const float*)d_in[1];
    const float* be = (const float*)d_in[2];
    const float* W1 = (const float*)d_in[3];
    const float* b1 = (const float*)d_in[4];
    const float* W2 = (const float*)d_in[5];
    const float* b2 = (const float*)d_in[6];
    const float* Wo = (const float*)d_in[7];
    const float* bo = (const float*)d_in[8];
    float* out = (float*)d_out;

    // ws layout (bytes): Bf bf16 [0, 98304) | Wob bf16 [98304, 98304+262144)
    if (ws_size < 98304u + 262144u) return;  // fail visibly, no UB
    unsigned short* Bf  = (unsigned short*)d_ws;
    unsigned short* Wob = (unsigned short*)((char*)d_ws + 98304);

    k_bf   <<<NL / 4, 256, 0, stream>>>(s, g, be, W2, b2, Wo, Bf, Wob);
    k_out_f<<<NL / 2, 256, 0, stream>>>(s, g, be, W1, b1, Wob, Bf, bo, out);
}